// Round 13
// baseline (160.723 us; speedup 1.0000x reference)
//
#include <hip/hip_runtime.h>
#include <math.h>

// SDN room acoustics: B=4 independent sims, one 256-thread block (4 waves) each.
// Lane layout (8-aligned node groups, bpermute-free):
//   lane 8n+j, j<5 : line PERM-source reader for line i=n*5+j (node n)
//   lane 8n+5     : mic FIR row of node n
//   lane 6        : direct src->mic path (group-0 pad; butterfly weight 0)
//   other pads    : idle (weights 0, never touch the ring)
// The line permutation is folded into the ring READ (lane for line i reads row
// PERM[i] with PERM[i]'s delay & node coeffs) so p_i = FIR + inj is lane-local.
// Per-node dots A=sum(v_j p_j), B=sum(micg q_j p_j) via DPP butterflies (pure
// VALU). wv_line = s*v - p, wv_mic = s*Wa - B, s = 2A/uu. FIR in direct form.
// OUTPUT: per-step mic+direct sum via a 6-op DPP full-wave reduction (zero
// contribution from non-mic lanes) -> lane 63 stores. No LDS staging at all.
//
// BANK EQUALIZATION: each ring row has exactly ONE reader lane; row rotation
// s[row] in [0,32) puts its reader's bank at (reader_lane & 31). Static since
// batch advance rotates banks uniformly (+28 mod 32) and LCAP == 0 mod 32.
//
// Batched by 28 steps (all D >= 29). One __syncthreads per batch orders
// writes(t) before reads(t+1). PREFETCH: batch t+1's u/x reads issue at the
// END of batch t; the barrier's lgkmcnt(0) drains them so FIR starts with
// zero wait. Prefetch-unsafe lanes (D < 42-shift+k0off) skip the prefetch
// and read after the barrier under an exec-masked branch.

#define NN    6
#define NLn   30
#define FIRN  7
#define TLEN  4000
#define LCAP  448                // ring capacity: 16*BATCH, == 0 mod 32
#define EXT   13                 // mirror extension (reads reach LCAP+12)
#define HEAD  32                 // per-row rotation headroom
#define RSTRA (LCAP + EXT + HEAD) // 493
#define PADX  264                // zero prefix: x[k-D] needs no bounds check
#define XPAD  64                 // zero tail: last partial batch reads x=0
#define NROW  37                 // 30 line rows + 6 mic rows + 1 dummy
#define BATCH 28
#define SPW   7                  // steps per wave
#define NU    (SPW + FIRN)       // 14 ring reads per batch per lane

template<int CTRL>
__device__ __forceinline__ float dpp_add(float x) {
    int m = __builtin_amdgcn_update_dpp(0, __float_as_int(x), CTRL, 0xF, 0xF, false);
    return x + __int_as_float(m);
}
// value from lane i^4 within each 8-lane group:
//   row_shr:4 writes dest banks 1,3 (lanes 4-7,12-15 <- 0-3,8-11)
//   row_shl:4 writes dest banks 0,2 (lanes 0-3,8-11 <- 4-7,12-15)
__device__ __forceinline__ float dpp_xquad(float x) {
    int xi = __float_as_int(x);
    int m = __builtin_amdgcn_update_dpp(0, xi, 0x114, 0xF, 0xA, false); // row_shr:4
    m     = __builtin_amdgcn_update_dpp(m, xi, 0x104, 0xF, 0x5, false); // row_shl:4
    return __int_as_float(m);
}
// full 64-lane sum -> lane 63 (zero-fill shifts; row_bcast cross-row)
__device__ __forceinline__ float wave_sum63(float x) {
    x = dpp_add<0x111>(x);   // row_shr:1
    x = dpp_add<0x112>(x);   // row_shr:2
    x = dpp_add<0x114>(x);   // row_shr:4
    x = dpp_add<0x118>(x);   // row_shr:8
    x = dpp_add<0x142>(x);   // row_bcast:15
    x = dpp_add<0x143>(x);   // row_bcast:31
    return x;
}

__global__ __launch_bounds__(256, 1)
void sdn_kernel(const float* __restrict__ x, const float* __restrict__ srcp,
                const float* __restrict__ micp, const float* __restrict__ jf,
                const float* __restrict__ jv, const float* __restrict__ pw,
                float* __restrict__ out, int T)
{
    const int b   = blockIdx.x;
    const int l   = threadIdx.x;
    const int wl  = l & 63;
    const int wid = l >> 6;

    __shared__ float  rows[NROW][RSTRA];
    __shared__ float  xl[PADX + TLEN + XPAD];
    __shared__ double nds[NN][3];
    __shared__ int    sshift[NROW];

    for (int i = l; i < NROW * RSTRA;       i += 256) (&rows[0][0])[i] = 0.f;
    for (int i = l; i < PADX + TLEN + XPAD; i += 256) xl[i] = 0.f;
    __syncthreads();
    for (int i = l; i < T; i += 256) xl[PADX + i] = x[i];

    const double room[3] = {4.0, 3.0, 2.5};
    double src[3] = {srcp[0], srcp[1], srcp[2]};
    double mic[3] = {micp[3*b+0], micp[3*b+1], micp[3*b+2]};

    if (l < NN) {
        int a = l >> 1;
        double w = (l & 1) ? room[a] : 0.0;
        double sa = (a == 0) ? src[0] : ((a == 1) ? src[1] : src[2]);
        double ma = (a == 0) ? mic[0] : ((a == 1) ? mic[1] : mic[2]);
        double ia = 2.0 * w - sa;
        double img0 = src[0], img1 = src[1], img2 = src[2];
        if (a == 0) img0 = ia; else if (a == 1) img1 = ia; else img2 = ia;
        double t = (w - ia) / (ma - ia);
        nds[l][0] = img0 + t * (mic[0] - img0);
        nds[l][1] = img1 + t * (mic[1] - img1);
        nds[l][2] = img2 + t * (mic[2] - img2);
    }
    __syncthreads();

    const double G = 343.0 / 16000.0;
    const int n  = (wl < 48) ? (wl >> 3) : 0;
    const int ir = wl & 7;
    const bool isline = (wl < 48) && (ir < 5);
    const bool ismic  = (wl < 48) && (ir == 5);
    const bool isdir  = (wl == 6);

    const int lineid = n * 5 + ir;                       // valid when isline
    #define PERMF(i) ((6*((i)+1) - ((i)%6) - 1) % NLn)
    const int srcl = PERMF(lineid % NLn);                // source line we read
    #undef PERMF
    const int ns = srcl / 5;                             // source line's node

    // own-node geometry (inj, micg, uu)
    double dx = nds[n][0] - src[0], dy = nds[n][1] - src[1], dz = nds[n][2] - src[2];
    double dsn = sqrt(dx*dx + dy*dy + dz*dz);
    dx = nds[n][0] - mic[0]; dy = nds[n][1] - mic[1]; dz = nds[n][2] - mic[2];
    double dnm = sqrt(dx*dx + dy*dy + dz*dz);
    dx = mic[0] - src[0]; dy = mic[1] - src[1]; dz = mic[2] - src[2];
    double dsm = sqrt(dx*dx + dy*dy + dz*dz);

    const int   Dsn  = (int)rint(dsn / G);
    const int   Dsm  = (int)rint(dsm / G);
    const float srcg = (float)(0.5 * G / dsn);
    const float micg = (float)(1.0 / (1.0 + dnm / dsn));
    const float dirg = (float)(1.0 / dsm);

    // delay of the row this lane READS
    int Dline;
    {
        int mm = srcl % 5;
        int m2 = mm + (mm >= ns ? 1 : 0);                // PAIRS of source line
        double ax = nds[ns][0] - nds[m2][0];
        double ay = nds[ns][1] - nds[m2][1];
        double az = nds[ns][2] - nds[m2][2];
        Dline = (int)rint(sqrt(ax*ax + ay*ay + az*az) / G);
    }
    const int Dmic = (int)rint(dnm / G);
    const int D = isline ? Dline : (ismic ? Dmic : 64);

    // injection (own node for lines; direct lane uses dsm path)
    float srcgl; int xoff;
    if (isline || ismic) { srcgl = srcg; xoff = PADX - Dsn; }
    else if (isdir)      { srcgl = dirg; xoff = PADX - Dsm; }
    else                 { srcgl = 0.f;  xoff = PADX; }
    const bool hasx = isline || ismic || isdir;

    // FIR coefficients: node of the row we read (source line's node / own node)
    const int nc = isline ? ns : n;
    const bool hasfir = isline || ismic;
    float c0,c1,c2,c3,c4,c5,c6,c7;
    {
        const float* f = jf + nc*(FIRN+1);
        c0 = hasfir ? f[7] : 0.f; c1 = hasfir ? f[6] : 0.f;
        c2 = hasfir ? f[5] : 0.f; c3 = hasfir ? f[4] : 0.f;
        c4 = hasfir ? f[3] : 0.f; c5 = hasfir ? f[2] : 0.f;
        c6 = hasfir ? f[1] : 0.f; c7 = hasfir ? f[0] : 0.f;
    }

    // butterfly weights and write-value constants
    const float uu = jv[n*5+0]*jv[n*5+0] + jv[n*5+1]*jv[n*5+1] + jv[n*5+2]*jv[n*5+2]
                   + jv[n*5+3]*jv[n*5+3] + jv[n*5+4]*jv[n*5+4];
    const float c2u = 2.0f / uu;
    const float vw = isline ? jv[n*5+ir] : 0.f;                  // v_j weight
    const float qw = isline ? micg * pw[n*5+ir] : 0.f;           // micg*q_j weight
    float Wa;
    if (isline) Wa = vw;
    else if (ismic) {
        Wa = micg * (jv[n*5+0]*pw[n*5+0] + jv[n*5+1]*pw[n*5+1] + jv[n*5+2]*pw[n*5+2]
                   + jv[n*5+3]*pw[n*5+3] + jv[n*5+4]*pw[n*5+4]);
    } else Wa = 0.f;

    // row ids
    const int rdrow = isline ? srcl : (ismic ? NLn + n : NROW - 1);
    const int wrrow = isline ? lineid : (ismic ? NLn + n : NROW - 1);
    const bool haswrite = isline || ismic;
    const bool hasout = ismic || isdir;       // contributes to output sum

    const int k0off = SPW * wid;                 // 0,7,14,21
    const int shift = isline ? 8 : 7;            // u window: k0-shift-D+j

    // ---- per-row bank rotation: reader bank == (reader lane & 31) ----
    if (wid == 0) {
        if (isline || ismic) {
            int v = ((wl & 31) - rdrow * RSTRA + shift + D) % 32;
            sshift[rdrow] = (v + 32) % 32;
        }
        if (l == 0) {
            int v = (6 - (NROW-1) * RSTRA + 7 + 64) % 32;
            sshift[NROW-1] = (v + 32) % 32;
        }
    }
    __syncthreads();

    float* rdbase = &rows[rdrow][0] + sshift[rdrow];
    float* wrbase = &rows[wrrow][0] + sshift[wrrow];
    const float* xpc = xl + xoff;
    float* outp = out + b * T;

    // prefetch-unsafe: newest prefetched step may be written by OTHER waves
    // during the overlapped batch.
    const bool needrr = (D < (42 - shift + k0off));
    const bool dopre  = hasfir && !needrr;

    int cur_off = ((k0off - shift - D) % LCAP + LCAP) % LCAP;
    int wp0 = 0;
    const int NB = (T + BATCH - 1) / BATCH;      // 143 for T=4000

    float u[NU], xq[SPW];
    #pragma unroll
    for (int j = 0; j < NU; ++j) u[j] = 0.f;     // pads/needrr keep 0 until read
    #pragma unroll
    for (int i = 0; i < SPW; ++i) xq[i] = 0.f;

    // prologue: prefetch batch 0 (ring is zero-initialized)
    if (dopre) {
        #pragma unroll
        for (int j = 0; j < NU; ++j) u[j] = rdbase[cur_off + j];
    }
    if (hasx) {
        #pragma unroll
        for (int i = 0; i < SPW; ++i) xq[i] = xpc[k0off + i];
    }
    int nxt_off = cur_off + BATCH; if (nxt_off >= LCAP) nxt_off -= LCAP;

    for (int t = 0; t < NB; ++t) {
        // ---- read for prefetch-unsafe lanes (execz-skipped when none) ----
        if (needrr) {
            #pragma unroll
            for (int j = 0; j < NU; ++j) u[j] = rdbase[cur_off + j];
        }

        // ---- B: direct-form FIRs + injection -> p ----
        float fir[SPW], inj[SPW], p[SPW];
        #pragma unroll
        for (int i = 0; i < SPW; ++i) {
            float a = c7 * u[i];
            a = fmaf(c6, u[i+1], a); a = fmaf(c5, u[i+2], a);
            a = fmaf(c4, u[i+3], a); a = fmaf(c3, u[i+4], a);
            a = fmaf(c2, u[i+5], a); a = fmaf(c1, u[i+6], a);
            a = fmaf(c0, u[i+7], a);
            inj[i] = srcgl * xq[i];
            if (isdir) a = inj[i];               // direct path output
            fir[i] = a;
            p[i] = a + inj[i];
        }

        // ---- C: DPP butterflies -> A,B per group; write values ----
        float wv[SPW];
        #pragma unroll
        for (int i = 0; i < SPW; ++i) {
            float tv = vw * p[i];
            float tq = qw * p[i];
            tv = dpp_add<0xB1>(tv); tq = dpp_add<0xB1>(tq);  // quad xor1
            tv = dpp_add<0x4E>(tv); tq = dpp_add<0x4E>(tq);  // quad xor2
            float Av = tv + dpp_xquad(tv);                    // + other quad
            float Bv = tq + dpp_xquad(tq);
            float s  = Av * c2u;
            wv[i] = fmaf(s, Wa, -(ismic ? Bv : p[i]));
        }

        // ---- D: ring writes (+ mirror) ----
        if (haswrite) {
            #pragma unroll
            for (int i = 0; i < SPW; ++i) wrbase[wp0 + k0off + i] = wv[i];
        }
        if (wp0 == 0) {                          // uniform, 1 in 16 batches
            if (haswrite) {
                #pragma unroll
                for (int i = 0; i < SPW; ++i)
                    if (k0off + i < EXT) wrbase[LCAP + k0off + i] = wv[i];
            }
        }

        // ---- prefetch batch t+1 (after ring writes; cross-wave races ----
        // ---- excluded by !needrr; x is read-only) ----
        cur_off = nxt_off;
        if (dopre) {
            #pragma unroll
            for (int j = 0; j < NU; ++j) u[j] = rdbase[cur_off + j];
        }
        if (hasx) {
            #pragma unroll
            for (int i = 0; i < SPW; ++i) xq[i] = xpc[(t+1)*BATCH + k0off + i];
        }
        nxt_off += BATCH; if (nxt_off >= LCAP) nxt_off -= LCAP;

        // ---- F: output via DPP full-wave sum (overlaps prefetch latency) ----
        #pragma unroll
        for (int i = 0; i < SPW; ++i) {
            float z = hasout ? fir[i] : 0.f;
            z = wave_sum63(z);
            int gidx = t * BATCH + k0off + i;
            if (wl == 63 && gidx < T) outp[gidx] = z;
        }

        wp0 += BATCH; if (wp0 >= LCAP) wp0 -= LCAP;
        __syncthreads();                         // writes(t) before reads(t+1)
    }
}

extern "C" void kernel_launch(void* const* d_in, const int* in_sizes, int n_in,
                              void* d_out, int out_size, void* d_ws, size_t ws_size,
                              hipStream_t stream)
{
    const float* x    = (const float*)d_in[0];
    const float* srcp = (const float*)d_in[1];
    const float* micp = (const float*)d_in[2];
    const float* jf   = (const float*)d_in[3];
    const float* jv   = (const float*)d_in[4];
    const float* pw   = (const float*)d_in[5];
    float* out = (float*)d_out;

    int T  = in_sizes[0];
    if (T > TLEN) T = TLEN;
    int Bc = in_sizes[2] / 3;

    sdn_kernel<<<Bc, 256, 0, stream>>>(x, srcp, micp, jf, jv, pw, out, T);
}

// Round 14
// 115.004 us; speedup vs baseline: 1.3975x; 1.3975x over previous
//
#include <hip/hip_runtime.h>
#include <math.h>

// SDN room acoustics: B=4 independent sims, one 256-thread block (4 waves) each.
// Lane layout (8-aligned node groups, bpermute-free):
//   lane 8n+j, j<5 : line PERM-source reader for line i=n*5+j (node n)
//   lane 8n+5     : mic FIR row of node n
//   lane 6        : direct src->mic path (group-0 pad; butterfly weight 0)
//   other pads    : idle (weights 0, read dummy row broadcast)
// The line permutation is folded into the ring READ (lane for line i reads row
// PERM[i] with PERM[i]'s delay & node coeffs) so p_i = FIR + inj is lane-local.
// Per-node dots A=sum(v_j p_j), B=sum(micg q_j p_j) via DPP butterflies (pure
// VALU). wv_line = s*v - p, wv_mic = s*Wa - B, s = 2A/uu. FIR in direct form.
// Output: mic FIRs + direct staged to small LDS (same-wave), lanes 0..6 sum
// and store coalesced.
//
// BANK EQUALIZATION: each ring row has exactly ONE reader lane; row rotation
// s[row] in [0,32) puts its reader's bank at (reader_lane & 31). Static since
// batch advance rotates banks uniformly (+28 mod 32) and LCAP == 0 mod 32.
//
// Batched by 28 steps (all D >= 29: mic/src confined to central half of room
// => d_nm >= 0.625 m => D >= 29). One __syncthreads per batch.
// POST-BARRIER PREFETCH: batch t+1's newest read position is
// (t+1)*28 + 21 + 13 - 7 - D <= (t+1)*28 - 2, i.e. written in batches <= t —
// so a prefetch issued right AFTER the barrier is unconditionally safe for
// every lane (no re-read machinery). Ring-slot reuse distance (<= 296+14) is
// < LCAP=448, so batch t+1's own writes never touch prefetched slots. The
// prefetch latency hides under the F phase + fine-grained lgkmcnt waits in
// the next batch's FIR.

#define NN    6
#define NLn   30
#define FIRN  7
#define TLEN  4000
#define LCAP  448                // ring capacity: 16*BATCH, == 0 mod 32
#define EXT   13                 // mirror extension (reads reach LCAP+12)
#define HEAD  32                 // per-row rotation headroom
#define RSTRA (LCAP + EXT + HEAD) // 493
#define PADX  264                // zero prefix: x[k-D] needs no bounds check
#define XPAD  64                 // zero tail: last batch prefetch reads x=0
#define NROW  37                 // 30 line rows + 6 mic rows + 1 dummy
#define BATCH 28
#define SPW   7                  // steps per wave
#define NU    (SPW + FIRN)       // 14 ring reads per batch per lane

template<int CTRL>
__device__ __forceinline__ float dpp_add(float x) {
    int m = __builtin_amdgcn_update_dpp(0, __float_as_int(x), CTRL, 0xF, 0xF, false);
    return x + __int_as_float(m);
}
// value from lane i^4 within each 8-lane group:
//   row_shr:4 writes dest banks 1,3 (lanes 4-7,12-15 <- 0-3,8-11)
//   row_shl:4 writes dest banks 0,2 (lanes 0-3,8-11 <- 4-7,12-15)
__device__ __forceinline__ float dpp_xquad(float x) {
    int xi = __float_as_int(x);
    int m = __builtin_amdgcn_update_dpp(0, xi, 0x114, 0xF, 0xA, false); // row_shr:4
    m     = __builtin_amdgcn_update_dpp(m, xi, 0x104, 0xF, 0x5, false); // row_shl:4
    return __int_as_float(m);
}

__global__ __launch_bounds__(256, 1)
void sdn_kernel(const float* __restrict__ x, const float* __restrict__ srcp,
                const float* __restrict__ micp, const float* __restrict__ jf,
                const float* __restrict__ jv, const float* __restrict__ pw,
                float* __restrict__ out, int T)
{
    const int b   = blockIdx.x;
    const int l   = threadIdx.x;
    const int wl  = l & 63;
    const int wid = l >> 6;

    __shared__ float  rows[NROW][RSTRA];
    __shared__ float  xl[PADX + TLEN + XPAD];
    __shared__ float  st[NN + 1][29];        // mic staging [row][step]
    __shared__ double nds[NN][3];
    __shared__ int    sshift[NROW];

    for (int i = l; i < NROW * RSTRA;       i += 256) (&rows[0][0])[i] = 0.f;
    for (int i = l; i < PADX + TLEN + XPAD; i += 256) xl[i] = 0.f;
    __syncthreads();
    for (int i = l; i < T; i += 256) xl[PADX + i] = x[i];

    const double room[3] = {4.0, 3.0, 2.5};
    double src[3] = {srcp[0], srcp[1], srcp[2]};
    double mic[3] = {micp[3*b+0], micp[3*b+1], micp[3*b+2]};

    if (l < NN) {
        int a = l >> 1;
        double w = (l & 1) ? room[a] : 0.0;
        double sa = (a == 0) ? src[0] : ((a == 1) ? src[1] : src[2]);
        double ma = (a == 0) ? mic[0] : ((a == 1) ? mic[1] : mic[2]);
        double ia = 2.0 * w - sa;
        double img0 = src[0], img1 = src[1], img2 = src[2];
        if (a == 0) img0 = ia; else if (a == 1) img1 = ia; else img2 = ia;
        double t = (w - ia) / (ma - ia);
        nds[l][0] = img0 + t * (mic[0] - img0);
        nds[l][1] = img1 + t * (mic[1] - img1);
        nds[l][2] = img2 + t * (mic[2] - img2);
    }
    __syncthreads();

    const double G = 343.0 / 16000.0;
    const int n  = (wl < 48) ? (wl >> 3) : 0;
    const int ir = wl & 7;
    const bool isline = (wl < 48) && (ir < 5);
    const bool ismic  = (wl < 48) && (ir == 5);
    const bool isdir  = (wl == 6);

    const int lineid = n * 5 + ir;                       // valid when isline
    #define PERMF(i) ((6*((i)+1) - ((i)%6) - 1) % NLn)
    const int srcl = PERMF(lineid % NLn);                // source line we read
    #undef PERMF
    const int ns = srcl / 5;                             // source line's node

    // own-node geometry (inj, micg, uu)
    double dx = nds[n][0] - src[0], dy = nds[n][1] - src[1], dz = nds[n][2] - src[2];
    double dsn = sqrt(dx*dx + dy*dy + dz*dz);
    dx = nds[n][0] - mic[0]; dy = nds[n][1] - mic[1]; dz = nds[n][2] - mic[2];
    double dnm = sqrt(dx*dx + dy*dy + dz*dz);
    dx = mic[0] - src[0]; dy = mic[1] - src[1]; dz = mic[2] - src[2];
    double dsm = sqrt(dx*dx + dy*dy + dz*dz);

    const int   Dsn  = (int)rint(dsn / G);
    const int   Dsm  = (int)rint(dsm / G);
    const float srcg = (float)(0.5 * G / dsn);
    const float micg = (float)(1.0 / (1.0 + dnm / dsn));
    const float dirg = (float)(1.0 / dsm);

    // delay of the row this lane READS
    int Dline;
    {
        int mm = srcl % 5;
        int m2 = mm + (mm >= ns ? 1 : 0);                // PAIRS of source line
        double ax = nds[ns][0] - nds[m2][0];
        double ay = nds[ns][1] - nds[m2][1];
        double az = nds[ns][2] - nds[m2][2];
        Dline = (int)rint(sqrt(ax*ax + ay*ay + az*az) / G);
    }
    const int Dmic = (int)rint(dnm / G);
    const int D = isline ? Dline : (ismic ? Dmic : 64);

    // injection (own node for lines; direct lane uses dsm path)
    float srcgl; int xoff;
    if (isline || ismic) { srcgl = srcg; xoff = PADX - Dsn; }
    else if (isdir)      { srcgl = dirg; xoff = PADX - Dsm; }
    else                 { srcgl = 0.f;  xoff = PADX; }

    // FIR coefficients: node of the row we read (source line's node / own node)
    const int nc = isline ? ns : n;
    const bool hasfir = isline || ismic;
    float c0,c1,c2,c3,c4,c5,c6,c7;
    {
        const float* f = jf + nc*(FIRN+1);
        c0 = hasfir ? f[7] : 0.f; c1 = hasfir ? f[6] : 0.f;
        c2 = hasfir ? f[5] : 0.f; c3 = hasfir ? f[4] : 0.f;
        c4 = hasfir ? f[3] : 0.f; c5 = hasfir ? f[2] : 0.f;
        c6 = hasfir ? f[1] : 0.f; c7 = hasfir ? f[0] : 0.f;
    }

    // butterfly weights and write-value constants
    const float uu = jv[n*5+0]*jv[n*5+0] + jv[n*5+1]*jv[n*5+1] + jv[n*5+2]*jv[n*5+2]
                   + jv[n*5+3]*jv[n*5+3] + jv[n*5+4]*jv[n*5+4];
    const float c2u = 2.0f / uu;
    const float vw = isline ? jv[n*5+ir] : 0.f;                  // v_j weight
    const float qw = isline ? micg * pw[n*5+ir] : 0.f;           // micg*q_j weight
    float Wa;
    if (isline) Wa = vw;
    else if (ismic) {
        Wa = micg * (jv[n*5+0]*pw[n*5+0] + jv[n*5+1]*pw[n*5+1] + jv[n*5+2]*pw[n*5+2]
                   + jv[n*5+3]*pw[n*5+3] + jv[n*5+4]*pw[n*5+4]);
    } else Wa = 0.f;

    // row ids
    const int rdrow = isline ? srcl : (ismic ? NLn + n : NROW - 1);
    const int wrrow = isline ? lineid : (ismic ? NLn + n : NROW - 1);
    const bool haswrite = isline || ismic;
    const bool hasstage = ismic || isdir;

    const int k0off = SPW * wid;                 // 0,7,14,21
    const int shift = isline ? 8 : 7;            // u window: k0-shift-D+j

    // ---- per-row bank rotation: reader bank == (reader lane & 31) ----
    if (wid == 0) {
        if (isline || ismic) {
            int v = ((wl & 31) - rdrow * RSTRA + shift + D) % 32;
            sshift[rdrow] = (v + 32) % 32;
        }
        if (l == 0) {
            int v = (6 - (NROW-1) * RSTRA + 7 + 64) % 32;
            sshift[NROW-1] = (v + 32) % 32;
        }
    }
    __syncthreads();

    float* rdbase = &rows[rdrow][0] + sshift[rdrow];
    float* wrbase = &rows[wrrow][0] + sshift[wrrow];
    float* strow  = st[ismic ? n : 6];
    const float* xpc = xl + xoff;
    float* outp = out + b * T;

    int cur_off = ((k0off - shift - D) % LCAP + LCAP) % LCAP;
    int wp0 = 0;
    const int NB = (T + BATCH - 1) / BATCH;      // 143 for T=4000

    float u[NU], xq[SPW];
    // prologue: prefetch batch 0 (ring is zero-initialized)
    #pragma unroll
    for (int j = 0; j < NU; ++j) u[j] = rdbase[cur_off + j];
    #pragma unroll
    for (int i = 0; i < SPW; ++i) xq[i] = xpc[k0off + i];
    int nxt_off = cur_off + BATCH; if (nxt_off >= LCAP) nxt_off -= LCAP;

    for (int t = 0; t < NB; ++t) {
        // ---- B: direct-form FIRs + injection -> p ----
        float fir[SPW], inj[SPW], p[SPW];
        #pragma unroll
        for (int i = 0; i < SPW; ++i) {
            float a = c7 * u[i];
            a = fmaf(c6, u[i+1], a); a = fmaf(c5, u[i+2], a);
            a = fmaf(c4, u[i+3], a); a = fmaf(c3, u[i+4], a);
            a = fmaf(c2, u[i+5], a); a = fmaf(c1, u[i+6], a);
            a = fmaf(c0, u[i+7], a);
            inj[i] = srcgl * xq[i];
            if (isdir) a = inj[i];               // direct path output
            fir[i] = a;
            p[i] = a + inj[i];
        }

        // ---- C: DPP butterflies -> A,B per group; write values ----
        float wv[SPW];
        #pragma unroll
        for (int i = 0; i < SPW; ++i) {
            float tv = vw * p[i];
            float tq = qw * p[i];
            tv = dpp_add<0xB1>(tv); tq = dpp_add<0xB1>(tq);  // quad xor1
            tv = dpp_add<0x4E>(tv); tq = dpp_add<0x4E>(tq);  // quad xor2
            float Av = tv + dpp_xquad(tv);                    // + other quad
            float Bv = tq + dpp_xquad(tq);
            float s  = Av * c2u;
            wv[i] = fmaf(s, Wa, -(ismic ? Bv : p[i]));
        }

        // ---- D: ring writes (+ mirror), mic staging ----
        if (haswrite) {
            #pragma unroll
            for (int i = 0; i < SPW; ++i) wrbase[wp0 + k0off + i] = wv[i];
        }
        if (wp0 == 0) {                          // uniform, 1 in 16 batches
            if (haswrite) {
                #pragma unroll
                for (int i = 0; i < SPW; ++i)
                    if (k0off + i < EXT) wrbase[LCAP + k0off + i] = wv[i];
            }
        }
        if (hasstage) {
            #pragma unroll
            for (int i = 0; i < SPW; ++i) strow[k0off + i] = fir[i];
        }

        __syncthreads();                         // batch-t writes visible

        // ---- prefetch batch t+1 (post-barrier: unconditionally safe, ----
        // ---- newest position <= (t+1)B-2; latency hides under F + B) ----
        cur_off = nxt_off;
        #pragma unroll
        for (int j = 0; j < NU; ++j) u[j] = rdbase[cur_off + j];
        #pragma unroll
        for (int i = 0; i < SPW; ++i) xq[i] = xpc[(t+1)*BATCH + k0off + i];
        nxt_off += BATCH; if (nxt_off >= LCAP) nxt_off -= LCAP;

        // ---- F: coalesced output (lanes 0..6 sum 7 staged rows; ----
        // ---- same-wave st ordering, reads trail the prefetch queue) ----
        if (wl < SPW) {
            int col  = k0off + wl;
            int gidx = t * BATCH + col;
            if (gidx < T) {
                float ssum = ((st[0][col] + st[1][col]) + (st[2][col] + st[3][col]))
                           + ((st[4][col] + st[5][col]) + st[6][col]);
                outp[gidx] = ssum;
            }
        }

        wp0 += BATCH; if (wp0 >= LCAP) wp0 -= LCAP;
    }
}

extern "C" void kernel_launch(void* const* d_in, const int* in_sizes, int n_in,
                              void* d_out, int out_size, void* d_ws, size_t ws_size,
                              hipStream_t stream)
{
    const float* x    = (const float*)d_in[0];
    const float* srcp = (const float*)d_in[1];
    const float* micp = (const float*)d_in[2];
    const float* jf   = (const float*)d_in[3];
    const float* jv   = (const float*)d_in[4];
    const float* pw   = (const float*)d_in[5];
    float* out = (float*)d_out;

    int T  = in_sizes[0];
    if (T > TLEN) T = TLEN;
    int Bc = in_sizes[2] / 3;

    sdn_kernel<<<Bc, 256, 0, stream>>>(x, srcp, micp, jf, jv, pw, out, T);
}